// Round 1
// baseline (10915.392 us; speedup 1.0000x reference)
//
#include <hip/hip_runtime.h>
#include <math.h>

#define SEQL 2048
#define H 1024
#define G3 3072
#define SENT 1.0e30f

__device__ __forceinline__ float sigmoidf_(float x){ return 1.0f/(1.0f+expf(-x)); }

// Fill h-exchange buffers with sentinel each call (graph-replay safe).
__global__ __launch_bounds__(256) void init_sent(float* p, int n4){
  int i = blockIdx.x*256 + threadIdx.x;
  if (i < n4) ((float4*)p)[i] = make_float4(SENT,SENT,SENT,SENT);
}

// embeds[t] = (ids[t]==1) ? 0 : embedding[ids[t]]
__global__ __launch_bounds__(256) void embed_kernel(const int* __restrict__ ids,
                                                    const float* __restrict__ emb,
                                                    float* __restrict__ out){
  int t = blockIdx.x;
  int id = ids[t];
  const float4* src = (const float4*)(emb + (size_t)id*H);
  float4* dst = (float4*)(out + (size_t)t*H);
  float4 v = (id == 1) ? make_float4(0.f,0.f,0.f,0.f) : src[threadIdx.x];
  dst[threadIdx.x] = v;
}

// C = A(2048x1024) * B^T + bias, B is 3072x1024 row-major (fwd at n<3072, rev after).
// 64x64 tile, 256 threads, 4x4 micro-tile, K-step 16.
__global__ __launch_bounds__(256) void gemm_kernel(const float* __restrict__ A,
  const float* __restrict__ WF, const float* __restrict__ WR,
  const float* __restrict__ bF, const float* __restrict__ bR,
  float* __restrict__ gxF, float* __restrict__ gxR)
{
  __shared__ float As[16][68];
  __shared__ float Bs[16][68];
  const int tid = threadIdx.x;
  const int n0 = blockIdx.x * 64;
  const int m0 = blockIdx.y * 64;
  const int dir = (n0 >= G3);
  const float* B    = dir ? WR : WF;
  const float* bias = dir ? bR : bF;
  float* C          = dir ? gxR : gxF;
  const int j0 = dir ? (n0 - G3) : n0;

  const int lr = tid >> 2;        // 0..63
  const int lc = (tid & 3) * 4;   // 0,4,8,12
  const int tx = tid & 15;        // 0..15
  const int ty = tid >> 4;        // 0..15

  float acc[4][4] = {};

  for (int k0 = 0; k0 < H; k0 += 16){
    float4 av = *(const float4*)(A + (size_t)(m0+lr)*H + k0 + lc);
    float4 bv = *(const float4*)(B + (size_t)(j0+lr)*H + k0 + lc);
    As[lc+0][lr]=av.x; As[lc+1][lr]=av.y; As[lc+2][lr]=av.z; As[lc+3][lr]=av.w;
    Bs[lc+0][lr]=bv.x; Bs[lc+1][lr]=bv.y; Bs[lc+2][lr]=bv.z; Bs[lc+3][lr]=bv.w;
    __syncthreads();
    #pragma unroll
    for (int kk=0; kk<16; ++kk){
      float a0=As[kk][ty*4+0], a1=As[kk][ty*4+1], a2=As[kk][ty*4+2], a3=As[kk][ty*4+3];
      float b0=Bs[kk][tx*4+0], b1=Bs[kk][tx*4+1], b2=Bs[kk][tx*4+2], b3=Bs[kk][tx*4+3];
      acc[0][0]=fmaf(a0,b0,acc[0][0]); acc[0][1]=fmaf(a0,b1,acc[0][1]);
      acc[0][2]=fmaf(a0,b2,acc[0][2]); acc[0][3]=fmaf(a0,b3,acc[0][3]);
      acc[1][0]=fmaf(a1,b0,acc[1][0]); acc[1][1]=fmaf(a1,b1,acc[1][1]);
      acc[1][2]=fmaf(a1,b2,acc[1][2]); acc[1][3]=fmaf(a1,b3,acc[1][3]);
      acc[2][0]=fmaf(a2,b0,acc[2][0]); acc[2][1]=fmaf(a2,b1,acc[2][1]);
      acc[2][2]=fmaf(a2,b2,acc[2][2]); acc[2][3]=fmaf(a2,b3,acc[2][3]);
      acc[3][0]=fmaf(a3,b0,acc[3][0]); acc[3][1]=fmaf(a3,b1,acc[3][1]);
      acc[3][2]=fmaf(a3,b2,acc[3][2]); acc[3][3]=fmaf(a3,b3,acc[3][3]);
    }
    __syncthreads();
  }

  #pragma unroll
  for (int u=0; u<4; ++u){
    float4 o;
    o.x = acc[u][0] + bias[j0+tx*4+0];
    o.y = acc[u][1] + bias[j0+tx*4+1];
    o.z = acc[u][2] + bias[j0+tx*4+2];
    o.w = acc[u][3] + bias[j0+tx*4+3];
    *(float4*)(C + (size_t)(m0+ty*4+u)*G3 + j0 + tx*4) = o;
  }
}

// Persistent scan: 256 WGs (128 per direction), each owns 8 h-elements
// (= 24 W_hh rows kept in VGPRs). h exchange via L3-coherent (agent-scope)
// atomics with sentinel poll-on-data.
__global__ __launch_bounds__(256) void scan_kernel(
  const float* __restrict__ gxF, const float* __restrict__ gxR,
  const float* __restrict__ WhF, const float* __restrict__ WhR,
  const float* __restrict__ bhF, const float* __restrict__ bhR,
  float* hFbuf, float* hRbuf, float* __restrict__ out)
{
  const int wgid = blockIdx.x;        // 0..255
  const int dir  = wgid >> 7;         // 0 fwd, 1 rev
  const int d    = wgid & 127;        // chunk id
  const int i0   = d * 8;
  const int tid  = threadIdx.x;
  const int lane = tid & 63;
  const int wv   = tid >> 6;          // wave 0..3

  const float* gx  = dir ? gxR : gxF;
  const float* Whh = dir ? WhR : WhF;
  const float* bhh = dir ? bhR : bhF;
  float* hbuf      = dir ? hRbuf : hFbuf;

  const int ia = i0 + 2*wv;
  const int ib = ia + 1;
  const int rows[6] = { ia, H+ia, 2*H+ia, ib, H+ib, 2*H+ib };

  float w[6][16];
  float bias[6];
  #pragma unroll
  for (int rr=0; rr<6; ++rr){
    const float* wp = Whh + (size_t)rows[rr]*H + lane;
    #pragma unroll
    for (int m=0; m<16; ++m) w[rr][m] = wp[m*64];
    bias[rr] = bhh[rows[rr]];
  }

  __shared__ float hs[H];

  for (int s=0; s<SEQL; ++s){
    if (s == 0){
      #pragma unroll
      for (int q=0;q<4;++q) hs[tid*4+q] = 0.0f;
    } else {
      float* src = hbuf + (size_t)(s-1)*H + tid*4;
      float v0,v1,v2,v3;
      do {
        v0 = __hip_atomic_load(src+0, __ATOMIC_RELAXED, __HIP_MEMORY_SCOPE_AGENT);
        v1 = __hip_atomic_load(src+1, __ATOMIC_RELAXED, __HIP_MEMORY_SCOPE_AGENT);
        v2 = __hip_atomic_load(src+2, __ATOMIC_RELAXED, __HIP_MEMORY_SCOPE_AGENT);
        v3 = __hip_atomic_load(src+3, __ATOMIC_RELAXED, __HIP_MEMORY_SCOPE_AGENT);
      } while (v0==SENT || v1==SENT || v2==SENT || v3==SENT);
      hs[tid*4+0]=v0; hs[tid*4+1]=v1; hs[tid*4+2]=v2; hs[tid*4+3]=v3;
    }
    __syncthreads();

    // per-lane strided h slice: k = lane + 64m (2-way LDS alias -> free)
    float hv[16];
    #pragma unroll
    for (int m=0; m<16; ++m) hv[m] = hs[lane + 64*m];

    float dots[6];
    #pragma unroll
    for (int rr=0; rr<6; ++rr){
      float acc = 0.f;
      #pragma unroll
      for (int m=0; m<16; ++m) acc = fmaf(w[rr][m], hv[m], acc);
      #pragma unroll
      for (int off=32; off>0; off>>=1) acc += __shfl_xor(acc, off);
      dots[rr] = acc + bias[rr];
    }

    const int t = dir ? (SEQL-1-s) : s;
    const float* gxt = gx + (size_t)t*G3;
    const float hpa = hs[ia], hpb = hs[ib];

    float ra = sigmoidf_(gxt[ia]       + dots[0]);
    float za = sigmoidf_(gxt[H+ia]     + dots[1]);
    float na = tanhf    (gxt[2*H+ia]   + ra*dots[2]);
    float hna = (1.f - za)*na + za*hpa;

    float rb = sigmoidf_(gxt[ib]       + dots[3]);
    float zb = sigmoidf_(gxt[H+ib]     + dots[4]);
    float nb = tanhf    (gxt[2*H+ib]   + rb*dots[5]);
    float hnb = (1.f - zb)*nb + zb*hpb;

    if (lane == 0){
      __hip_atomic_store(hbuf + (size_t)s*H + ia, hna, __ATOMIC_RELAXED, __HIP_MEMORY_SCOPE_AGENT);
      __hip_atomic_store(hbuf + (size_t)s*H + ib, hnb, __ATOMIC_RELAXED, __HIP_MEMORY_SCOPE_AGENT);
      out[(size_t)t*2048 + dir*H + ia] = hna;
      out[(size_t)t*2048 + dir*H + ib] = hnb;
      if (s == SEQL-1){
        const size_t base = (size_t)SEQL*2048;
        out[base + dir*H + ia] = hna;          // hidden
        out[base + dir*H + ib] = hnb;
        out[base + 2048 + dir*H + ia] = hna;   // projected_output
        out[base + 2048 + dir*H + ib] = hnb;
      }
    }
    __syncthreads();   // hs reused next step
  }
}

extern "C" void kernel_launch(void* const* d_in, const int* in_sizes, int n_in,
                              void* d_out, int out_size, void* d_ws, size_t ws_size,
                              hipStream_t stream)
{
  const int*   ids  = (const int*)  d_in[0];
  const float* emb  = (const float*)d_in[1];
  const float* WihF = (const float*)d_in[2];
  const float* WhhF = (const float*)d_in[3];
  const float* bihF = (const float*)d_in[4];
  const float* bhhF = (const float*)d_in[5];
  const float* WihR = (const float*)d_in[6];
  const float* WhhR = (const float*)d_in[7];
  const float* bihR = (const float*)d_in[8];
  const float* bhhR = (const float*)d_in[9];
  float* out = (float*)d_out;
  float* ws  = (float*)d_ws;

  float* embeds = ws;                       // 2048*1024
  float* gxF    = embeds + (size_t)SEQL*H;  // 2048*3072
  float* gxR    = gxF + (size_t)SEQL*G3;    // 2048*3072
  float* hF     = gxR + (size_t)SEQL*G3;    // 2048*1024
  float* hR     = hF + (size_t)SEQL*H;      // 2048*1024

  // sentinel-init h buffers: 2*2048*1024 floats = 1,048,576 float4
  init_sent<<<4096, 256, 0, stream>>>(hF, 1048576);
  embed_kernel<<<SEQL, 256, 0, stream>>>(ids, emb, embeds);
  dim3 gg(96, 32);
  gemm_kernel<<<gg, 256, 0, stream>>>(embeds, WihF, WihR, bihF, bihR, gxF, gxR);
  scan_kernel<<<256, 256, 0, stream>>>(gxF, gxR, WhhF, WhhR, bhhF, bhhR, hF, hR, out);
}

// Round 2
// 6688.969 us; speedup vs baseline: 1.6318x; 1.6318x over previous
//
#include <hip/hip_runtime.h>
#include <math.h>

#define SEQL 2048
#define H 1024
#define G3 3072
#define SENT 1.0e30f

__device__ __forceinline__ float sigmoidf_(float x){ return 1.0f/(1.0f+expf(-x)); }

// Cache-bypassing (sc0 sc1) 16B load: always served from coherence point.
__device__ __forceinline__ float4 ld_cohere(const float* p){
  float4 r;
  asm volatile("global_load_dwordx4 %0, %1, off sc0 sc1\n\t"
               "s_waitcnt vmcnt(0)"
               : "=&v"(r) : "v"(p) : "memory");
  return r;
}
// Cache-bypassing 8B store: immediately visible at coherence point.
__device__ __forceinline__ void st_cohere(float* p, float2 v){
  asm volatile("global_store_dwordx2 %0, %1, off sc0 sc1"
               :: "v"(p), "v"(v) : "memory");
}

// Fill h-exchange buffers with sentinel each call (graph-replay safe).
__global__ __launch_bounds__(256) void init_sent(float* p, int n4){
  int i = blockIdx.x*256 + threadIdx.x;
  if (i < n4) ((float4*)p)[i] = make_float4(SENT,SENT,SENT,SENT);
}

// embeds[t] = (ids[t]==1) ? 0 : embedding[ids[t]]
__global__ __launch_bounds__(256) void embed_kernel(const int* __restrict__ ids,
                                                    const float* __restrict__ emb,
                                                    float* __restrict__ out){
  int t = blockIdx.x;
  int id = ids[t];
  const float4* src = (const float4*)(emb + (size_t)id*H);
  float4* dst = (float4*)(out + (size_t)t*H);
  float4 v = (id == 1) ? make_float4(0.f,0.f,0.f,0.f) : src[threadIdx.x];
  dst[threadIdx.x] = v;
}

// C = A(2048x1024) * B^T + bias, B is 3072x1024 row-major (fwd blocks, then rev).
__global__ __launch_bounds__(256) void gemm_kernel(const float* __restrict__ A,
  const float* __restrict__ WF, const float* __restrict__ WR,
  const float* __restrict__ bF, const float* __restrict__ bR,
  float* __restrict__ gxF, float* __restrict__ gxR)
{
  __shared__ float As[16][68];
  __shared__ float Bs[16][68];
  const int tid = threadIdx.x;
  const int n0 = blockIdx.x * 64;
  const int m0 = blockIdx.y * 64;
  const int dir = (n0 >= G3);
  const float* B    = dir ? WR : WF;
  const float* bias = dir ? bR : bF;
  float* C          = dir ? gxR : gxF;
  const int j0 = dir ? (n0 - G3) : n0;

  const int lr = tid >> 2;
  const int lc = (tid & 3) * 4;
  const int tx = tid & 15;
  const int ty = tid >> 4;

  float acc[4][4] = {};

  for (int k0 = 0; k0 < H; k0 += 16){
    float4 av = *(const float4*)(A + (size_t)(m0+lr)*H + k0 + lc);
    float4 bv = *(const float4*)(B + (size_t)(j0+lr)*H + k0 + lc);
    As[lc+0][lr]=av.x; As[lc+1][lr]=av.y; As[lc+2][lr]=av.z; As[lc+3][lr]=av.w;
    Bs[lc+0][lr]=bv.x; Bs[lc+1][lr]=bv.y; Bs[lc+2][lr]=bv.z; Bs[lc+3][lr]=bv.w;
    __syncthreads();
    #pragma unroll
    for (int kk=0; kk<16; ++kk){
      float a0=As[kk][ty*4+0], a1=As[kk][ty*4+1], a2=As[kk][ty*4+2], a3=As[kk][ty*4+3];
      float b0=Bs[kk][tx*4+0], b1=Bs[kk][tx*4+1], b2=Bs[kk][tx*4+2], b3=Bs[kk][tx*4+3];
      acc[0][0]=fmaf(a0,b0,acc[0][0]); acc[0][1]=fmaf(a0,b1,acc[0][1]);
      acc[0][2]=fmaf(a0,b2,acc[0][2]); acc[0][3]=fmaf(a0,b3,acc[0][3]);
      acc[1][0]=fmaf(a1,b0,acc[1][0]); acc[1][1]=fmaf(a1,b1,acc[1][1]);
      acc[1][2]=fmaf(a1,b2,acc[1][2]); acc[1][3]=fmaf(a1,b3,acc[1][3]);
      acc[2][0]=fmaf(a2,b0,acc[2][0]); acc[2][1]=fmaf(a2,b1,acc[2][1]);
      acc[2][2]=fmaf(a2,b2,acc[2][2]); acc[2][3]=fmaf(a2,b3,acc[2][3]);
      acc[3][0]=fmaf(a3,b0,acc[3][0]); acc[3][1]=fmaf(a3,b1,acc[3][1]);
      acc[3][2]=fmaf(a3,b2,acc[3][2]); acc[3][3]=fmaf(a3,b3,acc[3][3]);
    }
    __syncthreads();
  }

  #pragma unroll
  for (int u=0; u<4; ++u){
    float4 o;
    o.x = acc[u][0] + bias[j0+tx*4+0];
    o.y = acc[u][1] + bias[j0+tx*4+1];
    o.z = acc[u][2] + bias[j0+tx*4+2];
    o.w = acc[u][3] + bias[j0+tx*4+3];
    *(float4*)(C + (size_t)(m0+ty*4+u)*G3 + j0 + tx*4) = o;
  }
}

// Persistent scan: 256 WGs (128 per direction), each owns 8 h-elements
// (24 W_hh rows in VGPRs — launch_bounds(256,1) unlocks the register budget).
// h exchange via explicit sc0/sc1 cache-bypassing loads/stores + sentinel poll.
__global__ __launch_bounds__(256, 1) void scan_kernel(
  const float* __restrict__ gxF, const float* __restrict__ gxR,
  const float* __restrict__ WhF, const float* __restrict__ WhR,
  const float* __restrict__ bhF, const float* __restrict__ bhR,
  float* hFbuf, float* hRbuf, float* __restrict__ out)
{
  const int wgid = blockIdx.x;        // 0..255
  const int dir  = wgid >> 7;         // 0 fwd, 1 rev
  const int d    = wgid & 127;        // chunk id
  const int i0   = d * 8;
  const int tid  = threadIdx.x;
  const int lane = tid & 63;
  const int wv   = tid >> 6;          // wave 0..3

  const float* gx  = dir ? gxR : gxF;
  const float* Whh = dir ? WhR : WhF;
  const float* bhh = dir ? bhR : bhF;
  float* hbuf      = dir ? hRbuf : hFbuf;

  const int ia = i0 + 2*wv;
  const int ib = ia + 1;
  const int rows[6] = { ia, H+ia, 2*H+ia, ib, H+ib, 2*H+ib };

  float w[6][16];
  float bias[6];
  #pragma unroll
  for (int rr=0; rr<6; ++rr){
    const float* wp = Whh + (size_t)rows[rr]*H + lane;
    #pragma unroll
    for (int m=0; m<16; ++m) w[rr][m] = wp[m*64];
    bias[rr] = bhh[rows[rr]];
  }

  __shared__ float hs[H];

  for (int s=0; s<SEQL; ++s){
    const int t = dir ? (SEQL-1-s) : s;
    const float* gxt = gx + (size_t)t*G3;
    // issue gx loads early: independent of h, latency hides under the poll
    float g0 = gxt[ia],     g1 = gxt[H+ia],   g2 = gxt[2*H+ia];
    float g3 = gxt[ib],     g4 = gxt[H+ib],   g5 = gxt[2*H+ib];

    if (s == 0){
      #pragma unroll
      for (int q=0;q<4;++q) hs[tid*4+q] = 0.0f;
    } else {
      const float* src = hbuf + (size_t)(s-1)*H + tid*4;
      float4 v;
      do { v = ld_cohere(src); }
      while (v.x==SENT || v.y==SENT || v.z==SENT || v.w==SENT);
      hs[tid*4+0]=v.x; hs[tid*4+1]=v.y; hs[tid*4+2]=v.z; hs[tid*4+3]=v.w;
    }
    __syncthreads();

    float hv[16];
    #pragma unroll
    for (int m=0; m<16; ++m) hv[m] = hs[lane + 64*m];

    float dots[6];
    #pragma unroll
    for (int rr=0; rr<6; ++rr){
      float acc = 0.f;
      #pragma unroll
      for (int m=0; m<16; ++m) acc = fmaf(w[rr][m], hv[m], acc);
      #pragma unroll
      for (int off=32; off>0; off>>=1) acc += __shfl_xor(acc, off);
      dots[rr] = acc + bias[rr];
    }

    const float hpa = hs[ia], hpb = hs[ib];

    float ra = sigmoidf_(g0 + dots[0]);
    float za = sigmoidf_(g1 + dots[1]);
    float na = tanhf    (g2 + ra*dots[2]);
    float hna = (1.f - za)*na + za*hpa;

    float rb = sigmoidf_(g3 + dots[3]);
    float zb = sigmoidf_(g4 + dots[4]);
    float nb = tanhf    (g5 + rb*dots[5]);
    float hnb = (1.f - zb)*nb + zb*hpb;

    if (lane == 0){
      st_cohere(hbuf + (size_t)s*H + ia, make_float2(hna, hnb));
      *(float2*)(out + (size_t)t*2048 + dir*H + ia) = make_float2(hna, hnb);
      if (s == SEQL-1){
        const size_t base = (size_t)SEQL*2048;
        *(float2*)(out + base + dir*H + ia)        = make_float2(hna, hnb); // hidden
        *(float2*)(out + base + 2048 + dir*H + ia) = make_float2(hna, hnb); // projected
      }
    }
    __syncthreads();   // hs reused next step
  }
}

extern "C" void kernel_launch(void* const* d_in, const int* in_sizes, int n_in,
                              void* d_out, int out_size, void* d_ws, size_t ws_size,
                              hipStream_t stream)
{
  const int*   ids  = (const int*)  d_in[0];
  const float* emb  = (const float*)d_in[1];
  const float* WihF = (const float*)d_in[2];
  const float* WhhF = (const float*)d_in[3];
  const float* bihF = (const float*)d_in[4];
  const float* bhhF = (const float*)d_in[5];
  const float* WihR = (const float*)d_in[6];
  const float* WhhR = (const float*)d_in[7];
  const float* bihR = (const float*)d_in[8];
  const float* bhhR = (const float*)d_in[9];
  float* out = (float*)d_out;
  float* ws  = (float*)d_ws;

  float* embeds = ws;                       // 2048*1024
  float* gxF    = embeds + (size_t)SEQL*H;  // 2048*3072
  float* gxR    = gxF + (size_t)SEQL*G3;    // 2048*3072
  float* hF     = gxR + (size_t)SEQL*G3;    // 2048*1024
  float* hR     = hF + (size_t)SEQL*H;      // 2048*1024

  init_sent<<<4096, 256, 0, stream>>>(hF, 1048576);
  embed_kernel<<<SEQL, 256, 0, stream>>>(ids, emb, embeds);
  dim3 gg(96, 32);
  gemm_kernel<<<gg, 256, 0, stream>>>(embeds, WihF, WihR, bihF, bihR, gxF, gxR);
  scan_kernel<<<256, 256, 0, stream>>>(gxF, gxR, WhhF, WhhR, bhhF, bhhR, hF, hR, out);
}

// Round 3
// 6235.725 us; speedup vs baseline: 1.7505x; 1.0727x over previous
//
#include <hip/hip_runtime.h>
#include <math.h>

#define SEQL 2048
#define H 1024
#define G3 3072
#define SENT 1.0e30f

__device__ __forceinline__ float sigmoidf_(float x){ return 1.0f/(1.0f+expf(-x)); }

// Cache-bypassing (sc0 sc1) 8B load: always served from coherence point.
__device__ __forceinline__ float2 ld_cohere2(const float* p){
  float2 r;
  asm volatile("global_load_dwordx2 %0, %1, off sc0 sc1\n\t"
               "s_waitcnt vmcnt(0)"
               : "=&v"(r) : "v"(p) : "memory");
  return r;
}
// Cache-bypassing 4B store: immediately visible at coherence point.
__device__ __forceinline__ void st_cohere1(float* p, float v){
  asm volatile("global_store_dword %0, %1, off sc0 sc1"
               :: "v"(p), "v"(v) : "memory");
}

// Fill h-exchange buffers with sentinel each call (graph-replay safe).
__global__ __launch_bounds__(256) void init_sent(float* p, int n4){
  int i = blockIdx.x*256 + threadIdx.x;
  if (i < n4) ((float4*)p)[i] = make_float4(SENT,SENT,SENT,SENT);
}

// embeds[t] = (ids[t]==1) ? 0 : embedding[ids[t]]
__global__ __launch_bounds__(256) void embed_kernel(const int* __restrict__ ids,
                                                    const float* __restrict__ emb,
                                                    float* __restrict__ out){
  int t = blockIdx.x;
  int id = ids[t];
  const float4* src = (const float4*)(emb + (size_t)id*H);
  float4* dst = (float4*)(out + (size_t)t*H);
  float4 v = (id == 1) ? make_float4(0.f,0.f,0.f,0.f) : src[threadIdx.x];
  dst[threadIdx.x] = v;
}

// C = A(2048x1024) * B^T + bias, B is 3072x1024 row-major (fwd blocks, then rev).
__global__ __launch_bounds__(256) void gemm_kernel(const float* __restrict__ A,
  const float* __restrict__ WF, const float* __restrict__ WR,
  const float* __restrict__ bF, const float* __restrict__ bR,
  float* __restrict__ gxF, float* __restrict__ gxR)
{
  __shared__ float As[16][68];
  __shared__ float Bs[16][68];
  const int tid = threadIdx.x;
  const int n0 = blockIdx.x * 64;
  const int m0 = blockIdx.y * 64;
  const int dir = (n0 >= G3);
  const float* B    = dir ? WR : WF;
  const float* bias = dir ? bR : bF;
  float* C          = dir ? gxR : gxF;
  const int j0 = dir ? (n0 - G3) : n0;

  const int lr = tid >> 2;
  const int lc = (tid & 3) * 4;
  const int tx = tid & 15;
  const int ty = tid >> 4;

  float acc[4][4] = {};

  for (int k0 = 0; k0 < H; k0 += 16){
    float4 av = *(const float4*)(A + (size_t)(m0+lr)*H + k0 + lc);
    float4 bv = *(const float4*)(B + (size_t)(j0+lr)*H + k0 + lc);
    As[lc+0][lr]=av.x; As[lc+1][lr]=av.y; As[lc+2][lr]=av.z; As[lc+3][lr]=av.w;
    Bs[lc+0][lr]=bv.x; Bs[lc+1][lr]=bv.y; Bs[lc+2][lr]=bv.z; Bs[lc+3][lr]=bv.w;
    __syncthreads();
    #pragma unroll
    for (int kk=0; kk<16; ++kk){
      float a0=As[kk][ty*4+0], a1=As[kk][ty*4+1], a2=As[kk][ty*4+2], a3=As[kk][ty*4+3];
      float b0=Bs[kk][tx*4+0], b1=Bs[kk][tx*4+1], b2=Bs[kk][tx*4+2], b3=Bs[kk][tx*4+3];
      acc[0][0]=fmaf(a0,b0,acc[0][0]); acc[0][1]=fmaf(a0,b1,acc[0][1]);
      acc[0][2]=fmaf(a0,b2,acc[0][2]); acc[0][3]=fmaf(a0,b3,acc[0][3]);
      acc[1][0]=fmaf(a1,b0,acc[1][0]); acc[1][1]=fmaf(a1,b1,acc[1][1]);
      acc[1][2]=fmaf(a1,b2,acc[1][2]); acc[1][3]=fmaf(a1,b3,acc[1][3]);
      acc[2][0]=fmaf(a2,b0,acc[2][0]); acc[2][1]=fmaf(a2,b1,acc[2][1]);
      acc[2][2]=fmaf(a2,b2,acc[2][2]); acc[2][3]=fmaf(a2,b3,acc[2][3]);
      acc[3][0]=fmaf(a3,b0,acc[3][0]); acc[3][1]=fmaf(a3,b1,acc[3][1]);
      acc[3][2]=fmaf(a3,b2,acc[3][2]); acc[3][3]=fmaf(a3,b3,acc[3][3]);
    }
    __syncthreads();
  }

  #pragma unroll
  for (int u=0; u<4; ++u){
    float4 o;
    o.x = acc[u][0] + bias[j0+tx*4+0];
    o.y = acc[u][1] + bias[j0+tx*4+1];
    o.z = acc[u][2] + bias[j0+tx*4+2];
    o.w = acc[u][3] + bias[j0+tx*4+3];
    *(float4*)(C + (size_t)(m0+ty*4+u)*G3 + j0 + tx*4) = o;
  }
}

// Persistent scan: 256 WGs x 512 threads (128 WG per direction).
// Each WG owns 8 h-elements; each WAVE owns one h-element = 3 W_hh rows.
// Per lane: w[3][16] = 48 weight floats, forced register-resident via
// opaque asm (defeats LLVM load-rematerialization seen in R2, VGPR=80<96).
// h exchange via sc0/sc1 cache-bypassing loads/stores + sentinel poll.
__global__ __launch_bounds__(512, 1) void scan_kernel(
  const float* __restrict__ gxF, const float* __restrict__ gxR,
  const float* __restrict__ WhF, const float* __restrict__ WhR,
  const float* __restrict__ bhF, const float* __restrict__ bhR,
  float* hFbuf, float* hRbuf, float* __restrict__ out)
{
  const int wgid = blockIdx.x;        // 0..255
  const int dir  = wgid >> 7;         // 0 fwd, 1 rev
  const int d    = wgid & 127;        // chunk id
  const int i0   = d * 8;
  const int tid  = threadIdx.x;       // 0..511
  const int lane = tid & 63;
  const int wv   = tid >> 6;          // wave 0..7

  const float* gx  = dir ? gxR : gxF;
  const float* Whh = dir ? WhR : WhF;
  const float* bhh = dir ? bhR : bhF;
  float* hbuf      = dir ? hRbuf : hFbuf;

  const int ia = i0 + wv;             // this wave's h-element
  const int rows[3] = { ia, H+ia, 2*H+ia };

  float w[3][16];
  float bias[3];
  #pragma unroll
  for (int rr=0; rr<3; ++rr){
    const float* wp = Whh + (size_t)rows[rr]*H + lane;
    #pragma unroll
    for (int m=0; m<16; ++m) w[rr][m] = wp[m*64];
    bias[rr] = bhh[rows[rr]];
  }
  // Make weight values opaque: compiler cannot rematerialize the loads,
  // must keep them in registers across the whole scan.
  #pragma unroll
  for (int rr=0; rr<3; ++rr){
    #pragma unroll
    for (int m=0; m<16; ++m) asm volatile("" : "+v"(w[rr][m]));
    asm volatile("" : "+v"(bias[rr]));
  }

  __shared__ float hs[H];

  for (int s=0; s<SEQL; ++s){
    const int t = dir ? (SEQL-1-s) : s;
    const float* gxt = gx + (size_t)t*G3;
    // wave-uniform gx loads, issued before the poll so latency hides under it
    float g0 = gxt[ia], g1 = gxt[H+ia], g2 = gxt[2*H+ia];

    if (s == 0){
      hs[tid*2+0] = 0.0f; hs[tid*2+1] = 0.0f;
    } else {
      const float* src = hbuf + (size_t)(s-1)*H + tid*2;
      float2 v;
      do { v = ld_cohere2(src); }
      while (v.x==SENT || v.y==SENT);
      hs[tid*2+0]=v.x; hs[tid*2+1]=v.y;
    }
    __syncthreads();

    float hv[16];
    #pragma unroll
    for (int m=0; m<16; ++m) hv[m] = hs[lane + 64*m];

    float dots[3];
    #pragma unroll
    for (int rr=0; rr<3; ++rr){
      float acc = 0.f;
      #pragma unroll
      for (int m=0; m<16; ++m) acc = fmaf(w[rr][m], hv[m], acc);
      #pragma unroll
      for (int off=32; off>0; off>>=1) acc += __shfl_xor(acc, off);
      dots[rr] = acc + bias[rr];
    }

    const float hp = hs[ia];
    float r = sigmoidf_(g0 + dots[0]);
    float z = sigmoidf_(g1 + dots[1]);
    float n = tanhf    (g2 + r*dots[2]);
    float hn = (1.f - z)*n + z*hp;

    if (lane == 0){
      st_cohere1(hbuf + (size_t)s*H + ia, hn);   // unblock consumers first
      out[(size_t)t*2048 + dir*H + ia] = hn;
      if (s == SEQL-1){
        const size_t base = (size_t)SEQL*2048;
        out[base + dir*H + ia]        = hn;   // hidden
        out[base + 2048 + dir*H + ia] = hn;   // projected_output
      }
    }
    __syncthreads();   // hs reused next step
  }
}

extern "C" void kernel_launch(void* const* d_in, const int* in_sizes, int n_in,
                              void* d_out, int out_size, void* d_ws, size_t ws_size,
                              hipStream_t stream)
{
  const int*   ids  = (const int*)  d_in[0];
  const float* emb  = (const float*)d_in[1];
  const float* WihF = (const float*)d_in[2];
  const float* WhhF = (const float*)d_in[3];
  const float* bihF = (const float*)d_in[4];
  const float* bhhF = (const float*)d_in[5];
  const float* WihR = (const float*)d_in[6];
  const float* WhhR = (const float*)d_in[7];
  const float* bihR = (const float*)d_in[8];
  const float* bhhR = (const float*)d_in[9];
  float* out = (float*)d_out;
  float* ws  = (float*)d_ws;

  float* embeds = ws;                       // 2048*1024
  float* gxF    = embeds + (size_t)SEQL*H;  // 2048*3072
  float* gxR    = gxF + (size_t)SEQL*G3;    // 2048*3072
  float* hF     = gxR + (size_t)SEQL*G3;    // 2048*1024
  float* hR     = hF + (size_t)SEQL*H;      // 2048*1024

  init_sent<<<4096, 256, 0, stream>>>(hF, 1048576);
  embed_kernel<<<SEQL, 256, 0, stream>>>(ids, emb, embeds);
  dim3 gg(96, 32);
  gemm_kernel<<<gg, 256, 0, stream>>>(embeds, WihF, WihR, bihF, bihR, gxF, gxR);
  scan_kernel<<<256, 512, 0, stream>>>(gxF, gxR, WhhF, WhhR, bhhF, bhhR, hF, hR, out);
}